// Round 10
// baseline (170.877 us; speedup 1.0000x reference)
//
#include <hip/hip_runtime.h>
#include <math.h>

#define B 32
#define N 512
#define DIN 768
#define DOUT 256
#define NEGV -9.0e15f
#define SLOPE 0.2f

typedef __bf16 bf16x8 __attribute__((ext_vector_type(8)));
typedef float f32x4 __attribute__((ext_vector_type(4)));
typedef unsigned short us8 __attribute__((ext_vector_type(8)));   // 16 B

__device__ __forceinline__ unsigned short f2b(float f) {
    union { float f; unsigned u; } v; v.f = f;
    unsigned r = v.u + 0x7FFF + ((v.u >> 16) & 1);
    return (unsigned short)(r >> 16);
}

// async 16B/lane global->LDS; lds ptr wave-uniform (lane i lands at base+i*16)
__device__ __forceinline__ void gload_lds16(const unsigned short* g, unsigned short* l) {
    __builtin_amdgcn_global_load_lds(
        (const __attribute__((address_space(1))) unsigned int*)(unsigned long long)(uintptr_t)g,
        (__attribute__((address_space(3))) unsigned int*)(uintptr_t)l,
        16, 0, 0);
}

// ---------------------------------------------------------------------------
// W transpose -> WT bf16 (64x64 LDS tiles).  48 blocks.
// ---------------------------------------------------------------------------
__global__ __launch_bounds__(256) void wt_kernel(
    const float* __restrict__ W, unsigned short* __restrict__ WT) {
    __shared__ unsigned short tile[64][65];
    const int t = threadIdx.x;
    int bid = blockIdx.x;
    int k0 = (bid % 12) * 64, n0 = (bid / 12) * 64;
    const int cl = t & 63, cg = t >> 6;
#pragma unroll
    for (int i = 0; i < 16; ++i) {
        int k = cg * 16 + i;
        tile[cl][k] = f2b(W[(size_t)(k0 + k) * DOUT + n0 + cl]);
    }
    __syncthreads();
#pragma unroll
    for (int i = 0; i < 16; ++i) {
        int n = cg * 16 + i;
        WT[(size_t)(n0 + n) * DIN + k0 + cl] = tile[n][cl];
    }
}

// ---------------------------------------------------------------------------
// GEMM1 (round-5 form, verified 164.3): Wh = h @ W + pos_emb -> WhT bf16
// (n-major), fused s1/s2.  Tile 128m x 64n, BK=64, 256 thr.
// A staged REG->LDS with inline fp32->bf16 convert.  Round-6's panel remap
// and T14 prefetch REVERTED (measured -6 us combined).
// ---------------------------------------------------------------------------
__global__ __launch_bounds__(256) void wh_mfma(
    const float* __restrict__ hF,            // [16384][768] fp32
    const unsigned short* __restrict__ WT,   // [256][768] bf16
    const int*   __restrict__ pos,           // [16384]
    const float* __restrict__ ptab,          // [512][256]
    const float* __restrict__ a1,
    const float* __restrict__ a2,
    unsigned short* __restrict__ WhT,        // [32][256][512]
    float* __restrict__ s1, float* __restrict__ s2)
{
    constexpr int K = DIN;
    __shared__ unsigned short smem[12288];
    unsigned short* As = smem;               // 128x64 bf16, swizzled
    unsigned short* Bs = smem + 8192;        // 64x64 bf16, swizzled
    unsigned short* tileT = smem;            // reused after k-loop

    const int t    = threadIdx.x;
    const int lane = t & 63;
    const int w    = t >> 6;
    const int lin  = blockIdx.x;
    const int m0   = (lin & 127) * 128;
    const int n0   = (lin >> 7) * 64;

    // A: per-chunk global row / pre-swizzled col-group, LDS write offset
    const float* gA[4];
    int aw[4];
#pragma unroll
    for (int i = 0; i < 4; ++i) {
        int c = i * 256 + t;
        int arow = c >> 3;
        int apos = (c & 7) ^ (arow & 7);
        gA[i] = hF + (size_t)(m0 + arow) * K + apos * 8;
        aw[i] = c * 8;                       // LDS short offset (16 B/chunk)
    }
    // B: pre-swizzled global source + linear LDS dest (global_load_lds)
    const unsigned short* gB[2];
    unsigned short* lB[2];
#pragma unroll
    for (int i = 0; i < 2; ++i) {
        int c = i * 256 + t;
        int brow = c >> 3;
        int bpos = (c & 7) ^ (brow & 7);
        gB[i] = WT + (size_t)(n0 + brow) * K + bpos * 8;
        lB[i] = Bs + (i * 256 + (t & 192)) * 8;
    }

    const int wm = (w & 1) * 64, wn = (w >> 1) * 32;
    const int l15 = lane & 15, q = lane >> 4;
    int aoff[2][4], boff[2][2];
#pragma unroll
    for (int kk = 0; kk < 2; ++kk) {
        int pg = kk * 4 + q;
#pragma unroll
        for (int i = 0; i < 4; ++i) {
            int rm = wm + i * 16 + l15;
            aoff[kk][i] = rm * 64 + ((pg ^ (rm & 7)) * 8);
        }
#pragma unroll
        for (int i = 0; i < 2; ++i) {
            int rn = wn + i * 16 + l15;
            boff[kk][i] = rn * 64 + ((pg ^ (rn & 7)) * 8);
        }
    }

    f32x4 acc[4][2];
#pragma unroll
    for (int i = 0; i < 4; ++i)
#pragma unroll
        for (int j = 0; j < 2; ++j) acc[i][j] = (f32x4){0.f, 0.f, 0.f, 0.f};

    for (int k0 = 0; k0 < K; k0 += 64) {
        // A: fp32 loads -> regs (8x dwordx4, issued together)
        float4 f0[4], f1[4];
#pragma unroll
        for (int i = 0; i < 4; ++i) {
            f0[i] = *(const float4*)(gA[i] + k0);
            f1[i] = *(const float4*)(gA[i] + k0 + 4);
        }
        // B: async direct-to-LDS
#pragma unroll
        for (int i = 0; i < 2; ++i) gload_lds16(gB[i] + k0, lB[i]);
        // A: convert (v_cvt_pk_bf16_f32 pairs) + ds_write_b128
#pragma unroll
        for (int i = 0; i < 4; ++i) {
            union { us8 v; __bf16 b[8]; } p;
            p.b[0] = (__bf16)f0[i].x; p.b[1] = (__bf16)f0[i].y;
            p.b[2] = (__bf16)f0[i].z; p.b[3] = (__bf16)f0[i].w;
            p.b[4] = (__bf16)f1[i].x; p.b[5] = (__bf16)f1[i].y;
            p.b[6] = (__bf16)f1[i].z; p.b[7] = (__bf16)f1[i].w;
            *(us8*)(As + aw[i]) = p.v;
        }
        __syncthreads();
#pragma unroll
        for (int kk = 0; kk < 2; ++kk) {
            bf16x8 af[4], bfr[2];
#pragma unroll
            for (int i = 0; i < 4; ++i) af[i] = *(const bf16x8*)(As + aoff[kk][i]);
#pragma unroll
            for (int i = 0; i < 2; ++i) bfr[i] = *(const bf16x8*)(Bs + boff[kk][i]);
#pragma unroll
            for (int mi = 0; mi < 4; ++mi)
#pragma unroll
                for (int ni = 0; ni < 2; ++ni)
                    acc[mi][ni] = __builtin_amdgcn_mfma_f32_16x16x32_bf16(
                        af[mi], bfr[ni], acc[mi][ni], 0, 0, 0);
        }
        __syncthreads();
    }

    // epilogue: + pos_emb; fused s1/s2 partials; transpose tile; coalesced write
    const float a1v[2] = { a1[n0 + wn + l15], a1[n0 + wn + 16 + l15] };
    const float a2v[2] = { a2[n0 + wn + l15], a2[n0 + wn + 16 + l15] };
#pragma unroll
    for (int mi = 0; mi < 4; ++mi) {
        const int jb = wm + mi * 16 + q * 4;
        float v2a[2][4];
#pragma unroll
        for (int ni = 0; ni < 2; ++ni) {
            const int nl = wn + ni * 16 + l15;
            ushort4 pk;
            unsigned short* pp = (unsigned short*)&pk;
#pragma unroll
            for (int r = 0; r < 4; ++r) {
                int m = m0 + jb + r;
                int p = pos[m];
                float val = acc[mi][ni][r] + ptab[(size_t)p * DOUT + n0 + nl];
                v2a[ni][r] = val;
                pp[r] = f2b(val);
            }
            *(ushort4*)&tileT[nl * 136 + jb] = pk;
        }
#pragma unroll
        for (int r = 0; r < 4; ++r) {
            float t1 = v2a[0][r] * a1v[0] + v2a[1][r] * a1v[1];
            float t2 = v2a[0][r] * a2v[0] + v2a[1][r] * a2v[1];
#pragma unroll
            for (int mk = 1; mk < 16; mk <<= 1) {
                t1 += __shfl_xor(t1, mk);
                t2 += __shfl_xor(t2, mk);
            }
            if (l15 == 0) {
                atomicAdd(&s1[m0 + jb + r], t1);
                atomicAdd(&s2[m0 + jb + r], t2);
            }
        }
    }
    __syncthreads();
    const int bb = m0 >> 9, j0 = m0 & 511;
#pragma unroll
    for (int rr = 0; rr < 4; ++rr) {
        int nl = (t >> 4) + rr * 16;
        int jl = (t & 15) * 8;
        us8 vv = *(const us8*)&tileT[nl * 136 + jl];
        *(us8*)&WhT[((size_t)bb * DOUT + n0 + nl) * N + j0 + jl] = vv;
    }
}

// ---------------------------------------------------------------------------
// Fused softmax + GEMM2.  One block per (b, 64-row m-tile); 1024 threads.
// B-strip hoist (unmeasured round-6 experiment, resubmitted): each wave's
// entire phase-2 B-strip (16 rows x 512 cols of WhT = 16x bf16x8 = 64 VGPR)
// is loaded ONCE at kernel start, while WhT is still L2-warm and phase 1
// provides ~10+ us of latency cover.  The K-loop is then pure LDS+MFMA —
// immune to L2 eviction from co-resident blocks' phase-1 adj/att streams
// (~84 MB/XCD through 4 MiB L2).  K-loop fully unrolled so bW[kk] is
// statically indexed (rule #20, no scratch).
// Phase 1: 16 threads/row, 32 cols each; 3 recompute passes, 32-bit adj mask.
// P LDS: addr(r,j): slot=j>>3, S = slot ^ (r&7) ^ (slot>>3),
//        addr = r*512 + S*8 + (j&7).
// XCD remap (T1): blockIdx i -> XCD i%8; XCD x handles bb in {4x..4x+3}.
// ---------------------------------------------------------------------------
__global__ __launch_bounds__(1024) void attn_hp(
    const float* __restrict__ s1,
    const float* __restrict__ s2,
    const int*   __restrict__ adj,
    const unsigned short* __restrict__ WhT,  // [32][256][512]
    float* __restrict__ att,                 // [32][512][512]
    float* __restrict__ hp)                  // [32][512][256]
{
    __shared__ unsigned short P[64 * 512];   // 64 KB

    const int t    = threadIdx.x;
    const int lane = t & 63;
    const int w    = t >> 6;                 // 0..15
    const int xid  = blockIdx.x & 7;         // XCD under round-robin dispatch
    const int rid  = blockIdx.x >> 3;        // 0..31
    const int bb   = xid * 4 + (rid >> 3);   // 4 batches per XCD
    const int m0   = (rid & 7) * 64;

    // ---- B-strip hoist: issue all 16 global loads NOW (hide under phase 1)
    const int wn  = w * 16;
    const int l15 = lane & 15, q = lane >> 4;
    const unsigned short* bRow = WhT + ((size_t)bb * DOUT + wn + l15) * N + q * 8;
    bf16x8 bW[16];
#pragma unroll
    for (int kk = 0; kk < 16; ++kk)
        bW[kk] = *(const bf16x8*)(bRow + kk * 32);

    // ---- phase 1: masked softmax, 16 threads/row, 32 cols each ----
    {
        const int r = t >> 4, c = t & 15;
        const size_t rowg = (size_t)bb * N + m0 + r;
        const float s1i = s1[rowg];
        const int4*   adjp = (const int4*)(adj + rowg * N) + c;       // [i*16]
        const float4* s2p  = (const float4*)(s2 + (size_t)bb * N) + c;

        // pass 1: adj -> 32-bit mask; masked max
        unsigned msk = 0u;
        float mx = -3.0e38f;
#pragma unroll
        for (int i = 0; i < 8; ++i) {
            int4 a = adjp[i * 16];
            float4 sv = s2p[i * 16];
            float v0 = s1i + sv.x; v0 = v0 > 0.f ? v0 : SLOPE * v0;
            float v1 = s1i + sv.y; v1 = v1 > 0.f ? v1 : SLOPE * v1;
            float v2 = s1i + sv.z; v2 = v2 > 0.f ? v2 : SLOPE * v2;
            float v3 = s1i + sv.w; v3 = v3 > 0.f ? v3 : SLOPE * v3;
            v0 = (a.x > 0) ? v0 : NEGV;
            v1 = (a.y > 0) ? v1 : NEGV;
            v2 = (a.z > 0) ? v2 : NEGV;
            v3 = (a.w > 0) ? v3 : NEGV;
            unsigned bits = (a.x > 0 ? 1u : 0u) | (a.y > 0 ? 2u : 0u) |
                            (a.z > 0 ? 4u : 0u) | (a.w > 0 ? 8u : 0u);
            msk |= bits << (i * 4);
            mx = fmaxf(mx, fmaxf(fmaxf(v0, v1), fmaxf(v2, v3)));
        }
#pragma unroll
        for (int mk = 1; mk < 16; mk <<= 1) mx = fmaxf(mx, __shfl_xor(mx, mk));

        // pass 2: recompute, sum of exp
        float sum = 0.f;
#pragma unroll
        for (int i = 0; i < 8; ++i) {
            float4 sv = s2p[i * 16];
            float v0 = s1i + sv.x; v0 = v0 > 0.f ? v0 : SLOPE * v0;
            float v1 = s1i + sv.y; v1 = v1 > 0.f ? v1 : SLOPE * v1;
            float v2 = s1i + sv.z; v2 = v2 > 0.f ? v2 : SLOPE * v2;
            float v3 = s1i + sv.w; v3 = v3 > 0.f ? v3 : SLOPE * v3;
            v0 = ((msk >> (i * 4 + 0)) & 1) ? v0 : NEGV;
            v1 = ((msk >> (i * 4 + 1)) & 1) ? v1 : NEGV;
            v2 = ((msk >> (i * 4 + 2)) & 1) ? v2 : NEGV;
            v3 = ((msk >> (i * 4 + 3)) & 1) ? v3 : NEGV;
            sum += __expf(v0 - mx) + __expf(v1 - mx) +
                   __expf(v2 - mx) + __expf(v3 - mx);
        }
#pragma unroll
        for (int mk = 1; mk < 16; mk <<= 1) sum += __shfl_xor(sum, mk);
        const float inv = 1.0f / sum;

        // pass 3: recompute, write att fp32 + P bf16 (swizzled)
        float4* attrow = (float4*)(att + rowg * N);
        unsigned short* Prow = P + r * 512;
        const int r7 = r & 7, chalf = (c & 1) * 4;
#pragma unroll
        for (int i = 0; i < 8; ++i) {
            float4 sv = s2p[i * 16];
            float v0 = s1i + sv.x; v0 = v0 > 0.f ? v0 : SLOPE * v0;
            float v1 = s1i + sv.y; v1 = v1 > 0.f ? v1 : SLOPE * v1;
            float v2 = s1i + sv.z; v2 = v2 > 0.f ? v2 : SLOPE * v2;
            float v3 = s1i + sv.w; v3 = v3 > 0.f ? v3 : SLOPE * v3;
            v0 = ((msk >> (i * 4 + 0)) & 1) ? v0 : NEGV;
            v1 = ((msk >> (i * 4 + 1)) & 1) ? v1 : NEGV;
            v2 = ((msk >> (i * 4 + 2)) & 1) ? v2 : NEGV;
            v3 = ((msk >> (i * 4 + 3)) & 1) ? v3 : NEGV;
            float e0 = __expf(v0 - mx) * inv;
            float e1 = __expf(v1 - mx) * inv;
            float e2 = __expf(v2 - mx) * inv;
            float e3 = __expf(v3 - mx) * inv;
            attrow[i * 16 + c] = (float4){e0, e1, e2, e3};
            int slot = i * 8 + (c >> 1);
            int S = slot ^ r7 ^ (slot >> 3);
            ushort4 pk = { f2b(e0), f2b(e1), f2b(e2), f2b(e3) };
            *(ushort4*)&Prow[S * 8 + chalf] = pk;
        }
    }
    __syncthreads();

    // ---- phase 2: hp[m0..m0+64][0..256] = P @ WhT^T, K = 512 ----
    // 16 waves; wave w computes the 64x16 strip at n = w*16.
    // B-frags already in registers (bW); pure LDS+MFMA loop.
    int rm7[4], rmBase[4];
#pragma unroll
    for (int mi = 0; mi < 4; ++mi) {
        int rm = mi * 16 + l15;
        rm7[mi] = rm & 7;
        rmBase[mi] = rm * 512;
    }

    f32x4 acc[4];
#pragma unroll
    for (int i = 0; i < 4; ++i) acc[i] = (f32x4){0.f, 0.f, 0.f, 0.f};

#pragma unroll
    for (int kk = 0; kk < 16; ++kk) {
        const int slot = kk * 4 + q;             // 0..63
        const int hi = slot >> 3;
        bf16x8 af[4];
#pragma unroll
        for (int mi = 0; mi < 4; ++mi) {
            int S = slot ^ rm7[mi] ^ hi;
            af[mi] = *(const bf16x8*)&P[rmBase[mi] + S * 8];
        }
#pragma unroll
        for (int mi = 0; mi < 4; ++mi)
            acc[mi] = __builtin_amdgcn_mfma_f32_16x16x32_bf16(
                af[mi], bW[kk], acc[mi], 0, 0, 0);
    }

#pragma unroll
    for (int mi = 0; mi < 4; ++mi) {
#pragma unroll
        for (int rr = 0; rr < 4; ++rr) {
            int m = m0 + mi * 16 + q * 4 + rr;
            int n = wn + l15;
            hp[((size_t)bb * N + m) * DOUT + n] = acc[mi][rr];
        }
    }
}

// ---------------------------------------------------------------------------
extern "C" void kernel_launch(void* const* d_in, const int* in_sizes, int n_in,
                              void* d_out, int out_size, void* d_ws, size_t ws_size,
                              hipStream_t stream) {
    const float* h         = (const float*)d_in[0];
    const int*   adj       = (const int*)  d_in[1];
    const int*   positions = (const int*)  d_in[2];
    const float* W         = (const float*)d_in[3];
    const float* a1        = (const float*)d_in[4];
    const float* a2        = (const float*)d_in[5];
    const float* pos_table = (const float*)d_in[6];

    float* out     = (float*)d_out;
    float* h_prime = out;                           // [B,N,DOUT]
    float* att     = out + (size_t)B * N * DOUT;    // [B,N,N]

    char* ws = (char*)d_ws;
    unsigned short* WT  = (unsigned short*)ws;                  // 0.39 MB
    unsigned short* WhT = (unsigned short*)(ws + 393216);       // 8.39 MB
    float*          s1  = (float*)(ws + 8781824);               // 64 KB
    float*          s2  = s1 + (size_t)B * N;

    // 0) zero s1/s2 for the fused atomics
    hipMemsetAsync(s1, 0, (size_t)2 * B * N * sizeof(float), stream);
    // 1) W -> WT bf16
    wt_kernel<<<48, 256, 0, stream>>>(W, WT);
    // 2) Wh GEMM (round-5 form) + pos_emb -> WhT bf16, fused s1/s2
    wh_mfma<<<512, 256, 0, stream>>>(h, WT, positions, pos_table, a1, a2, WhT, s1, s2);
    // 3) fused softmax + h_prime GEMM (B-strip in registers, XCD-colocated)
    attn_hp<<<256, 1024, 0, stream>>>(s1, s2, adj, WhT, att, h_prime);
}

// Round 12
// 163.080 us; speedup vs baseline: 1.0478x; 1.0478x over previous
//
#include <hip/hip_runtime.h>
#include <math.h>

#define B 32
#define N 512
#define DIN 768
#define DOUT 256
#define NEGV -9.0e15f
#define SLOPE 0.2f

typedef __bf16 bf16x8 __attribute__((ext_vector_type(8)));
typedef float f32x4 __attribute__((ext_vector_type(4)));
typedef int   i32x4 __attribute__((ext_vector_type(4)));
typedef unsigned short us8 __attribute__((ext_vector_type(8)));   // 16 B

__device__ __forceinline__ unsigned short f2b(float f) {
    union { float f; unsigned u; } v; v.f = f;
    unsigned r = v.u + 0x7FFF + ((v.u >> 16) & 1);
    return (unsigned short)(r >> 16);
}

// async 16B/lane global->LDS; lds ptr wave-uniform (lane i lands at base+i*16)
__device__ __forceinline__ void gload_lds16(const unsigned short* g, unsigned short* l) {
    __builtin_amdgcn_global_load_lds(
        (const __attribute__((address_space(1))) unsigned int*)(unsigned long long)(uintptr_t)g,
        (__attribute__((address_space(3))) unsigned int*)(uintptr_t)l,
        16, 0, 0);
}

// ---------------------------------------------------------------------------
// W transpose -> WT bf16 (64x64 LDS tiles).  48 blocks.
// ---------------------------------------------------------------------------
__global__ __launch_bounds__(256) void wt_kernel(
    const float* __restrict__ W, unsigned short* __restrict__ WT) {
    __shared__ unsigned short tile[64][65];
    const int t = threadIdx.x;
    int bid = blockIdx.x;
    int k0 = (bid % 12) * 64, n0 = (bid / 12) * 64;
    const int cl = t & 63, cg = t >> 6;
#pragma unroll
    for (int i = 0; i < 16; ++i) {
        int k = cg * 16 + i;
        tile[cl][k] = f2b(W[(size_t)(k0 + k) * DOUT + n0 + cl]);
    }
    __syncthreads();
#pragma unroll
    for (int i = 0; i < 16; ++i) {
        int n = cg * 16 + i;
        WT[(size_t)(n0 + n) * DIN + k0 + cl] = tile[n][cl];
    }
}

// ---------------------------------------------------------------------------
// GEMM1 (round-5 form, verified 164.3): Wh = h @ W + pos_emb -> WhT bf16
// (n-major), fused s1/s2.  Tile 128m x 64n, BK=64, 256 thr.
// A staged REG->LDS with inline fp32->bf16 convert.
// ---------------------------------------------------------------------------
__global__ __launch_bounds__(256) void wh_mfma(
    const float* __restrict__ hF,            // [16384][768] fp32
    const unsigned short* __restrict__ WT,   // [256][768] bf16
    const int*   __restrict__ pos,           // [16384]
    const float* __restrict__ ptab,          // [512][256]
    const float* __restrict__ a1,
    const float* __restrict__ a2,
    unsigned short* __restrict__ WhT,        // [32][256][512]
    float* __restrict__ s1, float* __restrict__ s2)
{
    constexpr int K = DIN;
    __shared__ unsigned short smem[12288];
    unsigned short* As = smem;               // 128x64 bf16, swizzled
    unsigned short* Bs = smem + 8192;        // 64x64 bf16, swizzled
    unsigned short* tileT = smem;            // reused after k-loop

    const int t    = threadIdx.x;
    const int lane = t & 63;
    const int w    = t >> 6;
    const int lin  = blockIdx.x;
    const int m0   = (lin & 127) * 128;
    const int n0   = (lin >> 7) * 64;

    // A: per-chunk global row / pre-swizzled col-group, LDS write offset
    const float* gA[4];
    int aw[4];
#pragma unroll
    for (int i = 0; i < 4; ++i) {
        int c = i * 256 + t;
        int arow = c >> 3;
        int apos = (c & 7) ^ (arow & 7);
        gA[i] = hF + (size_t)(m0 + arow) * K + apos * 8;
        aw[i] = c * 8;                       // LDS short offset (16 B/chunk)
    }
    // B: pre-swizzled global source + linear LDS dest (global_load_lds)
    const unsigned short* gB[2];
    unsigned short* lB[2];
#pragma unroll
    for (int i = 0; i < 2; ++i) {
        int c = i * 256 + t;
        int brow = c >> 3;
        int bpos = (c & 7) ^ (brow & 7);
        gB[i] = WT + (size_t)(n0 + brow) * K + bpos * 8;
        lB[i] = Bs + (i * 256 + (t & 192)) * 8;
    }

    const int wm = (w & 1) * 64, wn = (w >> 1) * 32;
    const int l15 = lane & 15, q = lane >> 4;
    int aoff[2][4], boff[2][2];
#pragma unroll
    for (int kk = 0; kk < 2; ++kk) {
        int pg = kk * 4 + q;
#pragma unroll
        for (int i = 0; i < 4; ++i) {
            int rm = wm + i * 16 + l15;
            aoff[kk][i] = rm * 64 + ((pg ^ (rm & 7)) * 8);
        }
#pragma unroll
        for (int i = 0; i < 2; ++i) {
            int rn = wn + i * 16 + l15;
            boff[kk][i] = rn * 64 + ((pg ^ (rn & 7)) * 8);
        }
    }

    f32x4 acc[4][2];
#pragma unroll
    for (int i = 0; i < 4; ++i)
#pragma unroll
        for (int j = 0; j < 2; ++j) acc[i][j] = (f32x4){0.f, 0.f, 0.f, 0.f};

    for (int k0 = 0; k0 < K; k0 += 64) {
        // A: fp32 loads -> regs (8x dwordx4, issued together)
        float4 f0[4], f1[4];
#pragma unroll
        for (int i = 0; i < 4; ++i) {
            f0[i] = *(const float4*)(gA[i] + k0);
            f1[i] = *(const float4*)(gA[i] + k0 + 4);
        }
        // B: async direct-to-LDS
#pragma unroll
        for (int i = 0; i < 2; ++i) gload_lds16(gB[i] + k0, lB[i]);
        // A: convert (v_cvt_pk_bf16_f32 pairs) + ds_write_b128
#pragma unroll
        for (int i = 0; i < 4; ++i) {
            union { us8 v; __bf16 b[8]; } p;
            p.b[0] = (__bf16)f0[i].x; p.b[1] = (__bf16)f0[i].y;
            p.b[2] = (__bf16)f0[i].z; p.b[3] = (__bf16)f0[i].w;
            p.b[4] = (__bf16)f1[i].x; p.b[5] = (__bf16)f1[i].y;
            p.b[6] = (__bf16)f1[i].z; p.b[7] = (__bf16)f1[i].w;
            *(us8*)(As + aw[i]) = p.v;
        }
        __syncthreads();
#pragma unroll
        for (int kk = 0; kk < 2; ++kk) {
            bf16x8 af[4], bfr[2];
#pragma unroll
            for (int i = 0; i < 4; ++i) af[i] = *(const bf16x8*)(As + aoff[kk][i]);
#pragma unroll
            for (int i = 0; i < 2; ++i) bfr[i] = *(const bf16x8*)(Bs + boff[kk][i]);
#pragma unroll
            for (int mi = 0; mi < 4; ++mi)
#pragma unroll
                for (int ni = 0; ni < 2; ++ni)
                    acc[mi][ni] = __builtin_amdgcn_mfma_f32_16x16x32_bf16(
                        af[mi], bfr[ni], acc[mi][ni], 0, 0, 0);
        }
        __syncthreads();
    }

    // epilogue: + pos_emb; fused s1/s2 partials; transpose tile; coalesced write
    const float a1v[2] = { a1[n0 + wn + l15], a1[n0 + wn + 16 + l15] };
    const float a2v[2] = { a2[n0 + wn + l15], a2[n0 + wn + 16 + l15] };
#pragma unroll
    for (int mi = 0; mi < 4; ++mi) {
        const int jb = wm + mi * 16 + q * 4;
        float v2a[2][4];
#pragma unroll
        for (int ni = 0; ni < 2; ++ni) {
            const int nl = wn + ni * 16 + l15;
            ushort4 pk;
            unsigned short* pp = (unsigned short*)&pk;
#pragma unroll
            for (int r = 0; r < 4; ++r) {
                int m = m0 + jb + r;
                int p = pos[m];
                float val = acc[mi][ni][r] + ptab[(size_t)p * DOUT + n0 + nl];
                v2a[ni][r] = val;
                pp[r] = f2b(val);
            }
            *(ushort4*)&tileT[nl * 136 + jb] = pk;
        }
#pragma unroll
        for (int r = 0; r < 4; ++r) {
            float t1 = v2a[0][r] * a1v[0] + v2a[1][r] * a1v[1];
            float t2 = v2a[0][r] * a2v[0] + v2a[1][r] * a2v[1];
#pragma unroll
            for (int mk = 1; mk < 16; mk <<= 1) {
                t1 += __shfl_xor(t1, mk);
                t2 += __shfl_xor(t2, mk);
            }
            if (l15 == 0) {
                atomicAdd(&s1[m0 + jb + r], t1);
                atomicAdd(&s2[m0 + jb + r], t2);
            }
        }
    }
    __syncthreads();
    const int bb = m0 >> 9, j0 = m0 & 511;
#pragma unroll
    for (int rr = 0; rr < 4; ++rr) {
        int nl = (t >> 4) + rr * 16;
        int jl = (t & 15) * 8;
        us8 vv = *(const us8*)&tileT[nl * 136 + jl];
        *(us8*)&WhT[((size_t)bb * DOUT + n0 + nl) * N + j0 + jl] = vv;
    }
}

// ---------------------------------------------------------------------------
// Fused softmax + GEMM2.  One block per (b, 64-row m-tile); 1024 threads.
// NT hints (round-11 fix: ext_vector types — HIP_vector_type rejected by the
// builtin) on the two never-reused streams: att writes (134 MB write-once),
// adj loads (33.5 MB read-once).  Keeps them from evicting WhT (8.4 MB,
// 8x reuse/XCD) + s2 from L2 -> phase-2 in-loop B-frag loads stay L2-hit.
// Zero-VGPR retest of the eviction theory (reg-hoist variant regressed on
// occupancy, round 10).
// Phase 1: 16 threads/row, 32 cols each; 3 recompute passes, 32-bit adj mask.
// Phase 2: K=512 MFMA loop, B-frags loaded in-loop from WhT (round-4/5 form).
// P LDS: addr(r,j): slot=j>>3, S = slot ^ (r&7) ^ (slot>>3),
//        addr = r*512 + S*8 + (j&7).
// XCD remap (T1): blockIdx i -> XCD i%8; XCD x handles bb in {4x..4x+3}.
// ---------------------------------------------------------------------------
__global__ __launch_bounds__(1024) void attn_hp(
    const float* __restrict__ s1,
    const float* __restrict__ s2,
    const int*   __restrict__ adj,
    const unsigned short* __restrict__ WhT,  // [32][256][512]
    float* __restrict__ att,                 // [32][512][512]
    float* __restrict__ hp)                  // [32][512][256]
{
    __shared__ unsigned short P[64 * 512];   // 64 KB

    const int t    = threadIdx.x;
    const int lane = t & 63;
    const int w    = t >> 6;                 // 0..15
    const int xid  = blockIdx.x & 7;         // XCD under round-robin dispatch
    const int rid  = blockIdx.x >> 3;        // 0..31
    const int bb   = xid * 4 + (rid >> 3);   // 4 batches per XCD
    const int m0   = (rid & 7) * 64;

    // ---- phase 1: masked softmax, 16 threads/row, 32 cols each ----
    {
        const int r = t >> 4, c = t & 15;
        const size_t rowg = (size_t)bb * N + m0 + r;
        const float s1i = s1[rowg];
        const i32x4* adjp = (const i32x4*)(adj + rowg * N) + c;       // [i*16]
        const float4* s2p = (const float4*)(s2 + (size_t)bb * N) + c;

        // pass 1: adj -> 32-bit mask (NT loads, read-once stream); masked max
        unsigned msk = 0u;
        float mx = -3.0e38f;
#pragma unroll
        for (int i = 0; i < 8; ++i) {
            i32x4 a = __builtin_nontemporal_load(adjp + i * 16);
            float4 sv = s2p[i * 16];
            float v0 = s1i + sv.x; v0 = v0 > 0.f ? v0 : SLOPE * v0;
            float v1 = s1i + sv.y; v1 = v1 > 0.f ? v1 : SLOPE * v1;
            float v2 = s1i + sv.z; v2 = v2 > 0.f ? v2 : SLOPE * v2;
            float v3 = s1i + sv.w; v3 = v3 > 0.f ? v3 : SLOPE * v3;
            v0 = (a.x > 0) ? v0 : NEGV;
            v1 = (a.y > 0) ? v1 : NEGV;
            v2 = (a.z > 0) ? v2 : NEGV;
            v3 = (a.w > 0) ? v3 : NEGV;
            unsigned bits = (a.x > 0 ? 1u : 0u) | (a.y > 0 ? 2u : 0u) |
                            (a.z > 0 ? 4u : 0u) | (a.w > 0 ? 8u : 0u);
            msk |= bits << (i * 4);
            mx = fmaxf(mx, fmaxf(fmaxf(v0, v1), fmaxf(v2, v3)));
        }
#pragma unroll
        for (int mk = 1; mk < 16; mk <<= 1) mx = fmaxf(mx, __shfl_xor(mx, mk));

        // pass 2: recompute, sum of exp
        float sum = 0.f;
#pragma unroll
        for (int i = 0; i < 8; ++i) {
            float4 sv = s2p[i * 16];
            float v0 = s1i + sv.x; v0 = v0 > 0.f ? v0 : SLOPE * v0;
            float v1 = s1i + sv.y; v1 = v1 > 0.f ? v1 : SLOPE * v1;
            float v2 = s1i + sv.z; v2 = v2 > 0.f ? v2 : SLOPE * v2;
            float v3 = s1i + sv.w; v3 = v3 > 0.f ? v3 : SLOPE * v3;
            v0 = ((msk >> (i * 4 + 0)) & 1) ? v0 : NEGV;
            v1 = ((msk >> (i * 4 + 1)) & 1) ? v1 : NEGV;
            v2 = ((msk >> (i * 4 + 2)) & 1) ? v2 : NEGV;
            v3 = ((msk >> (i * 4 + 3)) & 1) ? v3 : NEGV;
            sum += __expf(v0 - mx) + __expf(v1 - mx) +
                   __expf(v2 - mx) + __expf(v3 - mx);
        }
#pragma unroll
        for (int mk = 1; mk < 16; mk <<= 1) sum += __shfl_xor(sum, mk);
        const float inv = 1.0f / sum;

        // pass 3: recompute, write att fp32 (NT, write-once) + P bf16 (swizzled)
        f32x4* attrow = (f32x4*)(att + rowg * N);
        unsigned short* Prow = P + r * 512;
        const int r7 = r & 7, chalf = (c & 1) * 4;
#pragma unroll
        for (int i = 0; i < 8; ++i) {
            float4 sv = s2p[i * 16];
            float v0 = s1i + sv.x; v0 = v0 > 0.f ? v0 : SLOPE * v0;
            float v1 = s1i + sv.y; v1 = v1 > 0.f ? v1 : SLOPE * v1;
            float v2 = s1i + sv.z; v2 = v2 > 0.f ? v2 : SLOPE * v2;
            float v3 = s1i + sv.w; v3 = v3 > 0.f ? v3 : SLOPE * v3;
            v0 = ((msk >> (i * 4 + 0)) & 1) ? v0 : NEGV;
            v1 = ((msk >> (i * 4 + 1)) & 1) ? v1 : NEGV;
            v2 = ((msk >> (i * 4 + 2)) & 1) ? v2 : NEGV;
            v3 = ((msk >> (i * 4 + 3)) & 1) ? v3 : NEGV;
            float e0 = __expf(v0 - mx) * inv;
            float e1 = __expf(v1 - mx) * inv;
            float e2 = __expf(v2 - mx) * inv;
            float e3 = __expf(v3 - mx) * inv;
            __builtin_nontemporal_store((f32x4){e0, e1, e2, e3},
                                        attrow + i * 16 + c);
            int slot = i * 8 + (c >> 1);
            int S = slot ^ r7 ^ (slot >> 3);
            ushort4 pk = { f2b(e0), f2b(e1), f2b(e2), f2b(e3) };
            *(ushort4*)&Prow[S * 8 + chalf] = pk;
        }
    }
    __syncthreads();

    // ---- phase 2: hp[m0..m0+64][0..256] = P @ WhT^T, K = 512 ----
    // 16 waves; wave w computes the 64x16 strip at n = w*16.
    const int wn  = w * 16;
    const int l15 = lane & 15, q = lane >> 4;
    const unsigned short* bRow = WhT + ((size_t)bb * DOUT + wn + l15) * N + q * 8;
    int rm7[4], rmBase[4];
#pragma unroll
    for (int mi = 0; mi < 4; ++mi) {
        int rm = mi * 16 + l15;
        rm7[mi] = rm & 7;
        rmBase[mi] = rm * 512;
    }

    f32x4 acc[4];
#pragma unroll
    for (int i = 0; i < 4; ++i) acc[i] = (f32x4){0.f, 0.f, 0.f, 0.f};

#pragma unroll 4
    for (int k0 = 0; k0 < N; k0 += 32) {
        const int slot = (k0 >> 3) + q;          // 0..63
        const int hi = slot >> 3;
        bf16x8 af[4];
        bf16x8 bfr = *(const bf16x8*)(bRow + k0);
#pragma unroll
        for (int mi = 0; mi < 4; ++mi) {
            int S = slot ^ rm7[mi] ^ hi;
            af[mi] = *(const bf16x8*)&P[rmBase[mi] + S * 8];
        }
#pragma unroll
        for (int mi = 0; mi < 4; ++mi)
            acc[mi] = __builtin_amdgcn_mfma_f32_16x16x32_bf16(
                af[mi], bfr, acc[mi], 0, 0, 0);
    }

#pragma unroll
    for (int mi = 0; mi < 4; ++mi) {
#pragma unroll
        for (int rr = 0; rr < 4; ++rr) {
            int m = m0 + mi * 16 + q * 4 + rr;
            int n = wn + l15;
            hp[((size_t)bb * N + m) * DOUT + n] = acc[mi][rr];
        }
    }
}

// ---------------------------------------------------------------------------
extern "C" void kernel_launch(void* const* d_in, const int* in_sizes, int n_in,
                              void* d_out, int out_size, void* d_ws, size_t ws_size,
                              hipStream_t stream) {
    const float* h         = (const float*)d_in[0];
    const int*   adj       = (const int*)  d_in[1];
    const int*   positions = (const int*)  d_in[2];
    const float* W         = (const float*)d_in[3];
    const float* a1        = (const float*)d_in[4];
    const float* a2        = (const float*)d_in[5];
    const float* pos_table = (const float*)d_in[6];

    float* out     = (float*)d_out;
    float* h_prime = out;                           // [B,N,DOUT]
    float* att     = out + (size_t)B * N * DOUT;    // [B,N,N]

    char* ws = (char*)d_ws;
    unsigned short* WT  = (unsigned short*)ws;                  // 0.39 MB
    unsigned short* WhT = (unsigned short*)(ws + 393216);       // 8.39 MB
    float*          s1  = (float*)(ws + 8781824);               // 64 KB
    float*          s2  = s1 + (size_t)B * N;

    // 0) zero s1/s2 for the fused atomics
    (void)hipMemsetAsync(s1, 0, (size_t)2 * B * N * sizeof(float), stream);
    // 1) W -> WT bf16
    wt_kernel<<<48, 256, 0, stream>>>(W, WT);
    // 2) Wh GEMM (round-5 form) + pos_emb -> WhT bf16, fused s1/s2
    wh_mfma<<<512, 256, 0, stream>>>(h, WT, positions, pos_table, a1, a2, WhT, s1, s2);
    // 3) fused softmax + h_prime GEMM (NT streams, XCD-colocated)
    attn_hp<<<256, 1024, 0, stream>>>(s1, s2, adj, WhT, att, h_prime);
}

// Round 14
// 163.026 us; speedup vs baseline: 1.0482x; 1.0003x over previous
//
#include <hip/hip_runtime.h>
#include <math.h>

#define B 32
#define N 512
#define DIN 768
#define DOUT 256
#define NEGV -9.0e15f
#define SLOPE 0.2f

typedef __bf16 bf16x8 __attribute__((ext_vector_type(8)));
typedef float f32x4 __attribute__((ext_vector_type(4)));
typedef int   i32x4 __attribute__((ext_vector_type(4)));
typedef unsigned short us8 __attribute__((ext_vector_type(8)));   // 16 B

__device__ __forceinline__ unsigned short f2b(float f) {
    union { float f; unsigned u; } v; v.f = f;
    unsigned r = v.u + 0x7FFF + ((v.u >> 16) & 1);
    return (unsigned short)(r >> 16);
}

// async 16B/lane global->LDS; lds ptr wave-uniform (lane i lands at base+i*16)
__device__ __forceinline__ void gload_lds16(const unsigned short* g, unsigned short* l) {
    __builtin_amdgcn_global_load_lds(
        (const __attribute__((address_space(1))) unsigned int*)(unsigned long long)(uintptr_t)g,
        (__attribute__((address_space(3))) unsigned int*)(uintptr_t)l,
        16, 0, 0);
}

// ---------------------------------------------------------------------------
// W transpose -> WT bf16 (64x64 LDS tiles).  48 blocks.
// ---------------------------------------------------------------------------
__global__ __launch_bounds__(256) void wt_kernel(
    const float* __restrict__ W, unsigned short* __restrict__ WT) {
    __shared__ unsigned short tile[64][65];
    const int t = threadIdx.x;
    int bid = blockIdx.x;
    int k0 = (bid % 12) * 64, n0 = (bid / 12) * 64;
    const int cl = t & 63, cg = t >> 6;
#pragma unroll
    for (int i = 0; i < 16; ++i) {
        int k = cg * 16 + i;
        tile[cl][k] = f2b(W[(size_t)(k0 + k) * DOUT + n0 + cl]);
    }
    __syncthreads();
#pragma unroll
    for (int i = 0; i < 16; ++i) {
        int n = cg * 16 + i;
        WT[(size_t)(n0 + n) * DIN + k0 + cl] = tile[n][cl];
    }
}

// ---------------------------------------------------------------------------
// GEMM1 (round-5 form, verified): Wh = h @ W + pos_emb -> WhT bf16
// (n-major), fused s1/s2.  Tile 128m x 64n, BK=64, 256 thr.
// A staged REG->LDS with inline fp32->bf16 convert.
// ---------------------------------------------------------------------------
__global__ __launch_bounds__(256) void wh_mfma(
    const float* __restrict__ hF,            // [16384][768] fp32
    const unsigned short* __restrict__ WT,   // [256][768] bf16
    const int*   __restrict__ pos,           // [16384]
    const float* __restrict__ ptab,          // [512][256]
    const float* __restrict__ a1,
    const float* __restrict__ a2,
    unsigned short* __restrict__ WhT,        // [32][256][512]
    float* __restrict__ s1, float* __restrict__ s2)
{
    constexpr int K = DIN;
    __shared__ unsigned short smem[12288];
    unsigned short* As = smem;               // 128x64 bf16, swizzled
    unsigned short* Bs = smem + 8192;        // 64x64 bf16, swizzled
    unsigned short* tileT = smem;            // reused after k-loop

    const int t    = threadIdx.x;
    const int lane = t & 63;
    const int w    = t >> 6;
    const int lin  = blockIdx.x;
    const int m0   = (lin & 127) * 128;
    const int n0   = (lin >> 7) * 64;

    // A: per-chunk global row / pre-swizzled col-group, LDS write offset
    const float* gA[4];
    int aw[4];
#pragma unroll
    for (int i = 0; i < 4; ++i) {
        int c = i * 256 + t;
        int arow = c >> 3;
        int apos = (c & 7) ^ (arow & 7);
        gA[i] = hF + (size_t)(m0 + arow) * K + apos * 8;
        aw[i] = c * 8;                       // LDS short offset (16 B/chunk)
    }
    // B: pre-swizzled global source + linear LDS dest (global_load_lds)
    const unsigned short* gB[2];
    unsigned short* lB[2];
#pragma unroll
    for (int i = 0; i < 2; ++i) {
        int c = i * 256 + t;
        int brow = c >> 3;
        int bpos = (c & 7) ^ (brow & 7);
        gB[i] = WT + (size_t)(n0 + brow) * K + bpos * 8;
        lB[i] = Bs + (i * 256 + (t & 192)) * 8;
    }

    const int wm = (w & 1) * 64, wn = (w >> 1) * 32;
    const int l15 = lane & 15, q = lane >> 4;
    int aoff[2][4], boff[2][2];
#pragma unroll
    for (int kk = 0; kk < 2; ++kk) {
        int pg = kk * 4 + q;
#pragma unroll
        for (int i = 0; i < 4; ++i) {
            int rm = wm + i * 16 + l15;
            aoff[kk][i] = rm * 64 + ((pg ^ (rm & 7)) * 8);
        }
#pragma unroll
        for (int i = 0; i < 2; ++i) {
            int rn = wn + i * 16 + l15;
            boff[kk][i] = rn * 64 + ((pg ^ (rn & 7)) * 8);
        }
    }

    f32x4 acc[4][2];
#pragma unroll
    for (int i = 0; i < 4; ++i)
#pragma unroll
        for (int j = 0; j < 2; ++j) acc[i][j] = (f32x4){0.f, 0.f, 0.f, 0.f};

    for (int k0 = 0; k0 < K; k0 += 64) {
        // A: fp32 loads -> regs (8x dwordx4, issued together)
        float4 f0[4], f1[4];
#pragma unroll
        for (int i = 0; i < 4; ++i) {
            f0[i] = *(const float4*)(gA[i] + k0);
            f1[i] = *(const float4*)(gA[i] + k0 + 4);
        }
        // B: async direct-to-LDS
#pragma unroll
        for (int i = 0; i < 2; ++i) gload_lds16(gB[i] + k0, lB[i]);
        // A: convert (v_cvt_pk_bf16_f32 pairs) + ds_write_b128
#pragma unroll
        for (int i = 0; i < 4; ++i) {
            union { us8 v; __bf16 b[8]; } p;
            p.b[0] = (__bf16)f0[i].x; p.b[1] = (__bf16)f0[i].y;
            p.b[2] = (__bf16)f0[i].z; p.b[3] = (__bf16)f0[i].w;
            p.b[4] = (__bf16)f1[i].x; p.b[5] = (__bf16)f1[i].y;
            p.b[6] = (__bf16)f1[i].z; p.b[7] = (__bf16)f1[i].w;
            *(us8*)(As + aw[i]) = p.v;
        }
        __syncthreads();
#pragma unroll
        for (int kk = 0; kk < 2; ++kk) {
            bf16x8 af[4], bfr[2];
#pragma unroll
            for (int i = 0; i < 4; ++i) af[i] = *(const bf16x8*)(As + aoff[kk][i]);
#pragma unroll
            for (int i = 0; i < 2; ++i) bfr[i] = *(const bf16x8*)(Bs + boff[kk][i]);
#pragma unroll
            for (int mi = 0; mi < 4; ++mi)
#pragma unroll
                for (int ni = 0; ni < 2; ++ni)
                    acc[mi][ni] = __builtin_amdgcn_mfma_f32_16x16x32_bf16(
                        af[mi], bfr[ni], acc[mi][ni], 0, 0, 0);
        }
        __syncthreads();
    }

    // epilogue: + pos_emb; fused s1/s2 partials; transpose tile; coalesced write
    const float a1v[2] = { a1[n0 + wn + l15], a1[n0 + wn + 16 + l15] };
    const float a2v[2] = { a2[n0 + wn + l15], a2[n0 + wn + 16 + l15] };
#pragma unroll
    for (int mi = 0; mi < 4; ++mi) {
        const int jb = wm + mi * 16 + q * 4;
        float v2a[2][4];
#pragma unroll
        for (int ni = 0; ni < 2; ++ni) {
            const int nl = wn + ni * 16 + l15;
            ushort4 pk;
            unsigned short* pp = (unsigned short*)&pk;
#pragma unroll
            for (int r = 0; r < 4; ++r) {
                int m = m0 + jb + r;
                int p = pos[m];
                float val = acc[mi][ni][r] + ptab[(size_t)p * DOUT + n0 + nl];
                v2a[ni][r] = val;
                pp[r] = f2b(val);
            }
            *(ushort4*)&tileT[nl * 136 + jb] = pk;
        }
#pragma unroll
        for (int r = 0; r < 4; ++r) {
            float t1 = v2a[0][r] * a1v[0] + v2a[1][r] * a1v[1];
            float t2 = v2a[0][r] * a2v[0] + v2a[1][r] * a2v[1];
#pragma unroll
            for (int mk = 1; mk < 16; mk <<= 1) {
                t1 += __shfl_xor(t1, mk);
                t2 += __shfl_xor(t2, mk);
            }
            if (l15 == 0) {
                atomicAdd(&s1[m0 + jb + r], t1);
                atomicAdd(&s2[m0 + jb + r], t2);
            }
        }
    }
    __syncthreads();
    const int bb = m0 >> 9, j0 = m0 & 511;
#pragma unroll
    for (int rr = 0; rr < 4; ++rr) {
        int nl = (t >> 4) + rr * 16;
        int jl = (t & 15) * 8;
        us8 vv = *(const us8*)&tileT[nl * 136 + jl];
        *(us8*)&WhT[((size_t)bb * DOUT + n0 + nl) * N + j0 + jl] = vv;
    }
}

// ---------------------------------------------------------------------------
// Fused softmax + GEMM2.  One block per (b, 64-row m-tile); 1024 threads.
// NT hints KEPT (round-12, 163.1 best).  Single-compute-pass softmax
// (unmeasured round-12 experiment, resubmitted): the 32 per-thread
// masked-leakyrelu values are computed ONCE and cached in ev[8] (f32x4,
// statically indexed), then exp'd in place, then scaled+stored.  Eliminates
// 2x s2/adj re-reads, 2x leakyrelu+mask chains, and one full set of 32 exps
// per thread.  msk bitfield gone: mask baked into cached v (exp(NEGV-mx)==0).
// +32 VGPR over a short span only (dies before phase 2; peak ~90 < 128).
// Phase 2: K=512 MFMA loop, B-frags loaded in-loop from WhT (verified form).
// P LDS: addr(r,j): slot=j>>3, S = slot ^ (r&7) ^ (slot>>3),
//        addr = r*512 + S*8 + (j&7).
// XCD remap (T1): blockIdx i -> XCD i%8; XCD x handles bb in {4x..4x+3}.
// ---------------------------------------------------------------------------
__global__ __launch_bounds__(1024) void attn_hp(
    const float* __restrict__ s1,
    const float* __restrict__ s2,
    const int*   __restrict__ adj,
    const unsigned short* __restrict__ WhT,  // [32][256][512]
    float* __restrict__ att,                 // [32][512][512]
    float* __restrict__ hp)                  // [32][512][256]
{
    __shared__ unsigned short P[64 * 512];   // 64 KB

    const int t    = threadIdx.x;
    const int lane = t & 63;
    const int w    = t >> 6;                 // 0..15
    const int xid  = blockIdx.x & 7;         // XCD under round-robin dispatch
    const int rid  = blockIdx.x >> 3;        // 0..31
    const int bb   = xid * 4 + (rid >> 3);   // 4 batches per XCD
    const int m0   = (rid & 7) * 64;

    // ---- phase 1: masked softmax, 16 threads/row, 32 cols each ----
    {
        const int r = t >> 4, c = t & 15;
        const size_t rowg = (size_t)bb * N + m0 + r;
        const float s1i = s1[rowg];
        const i32x4* adjp = (const i32x4*)(adj + rowg * N) + c;       // [i*16]
        const float4* s2p = (const float4*)(s2 + (size_t)bb * N) + c;

        // single compute pass: masked leakyrelu -> ev[8] (registers) + max
        f32x4 ev[8];
        float mx = -3.0e38f;
#pragma unroll
        for (int i = 0; i < 8; ++i) {
            i32x4 a = __builtin_nontemporal_load(adjp + i * 16);
            float4 sv = s2p[i * 16];
            float v0 = s1i + sv.x; v0 = v0 > 0.f ? v0 : SLOPE * v0;
            float v1 = s1i + sv.y; v1 = v1 > 0.f ? v1 : SLOPE * v1;
            float v2 = s1i + sv.z; v2 = v2 > 0.f ? v2 : SLOPE * v2;
            float v3 = s1i + sv.w; v3 = v3 > 0.f ? v3 : SLOPE * v3;
            v0 = (a.x > 0) ? v0 : NEGV;
            v1 = (a.y > 0) ? v1 : NEGV;
            v2 = (a.z > 0) ? v2 : NEGV;
            v3 = (a.w > 0) ? v3 : NEGV;
            ev[i] = (f32x4){v0, v1, v2, v3};
            mx = fmaxf(mx, fmaxf(fmaxf(v0, v1), fmaxf(v2, v3)));
        }
#pragma unroll
        for (int mk = 1; mk < 16; mk <<= 1) mx = fmaxf(mx, __shfl_xor(mx, mk));

        // exp in place + sum (no loads, no recompute)
        float sum = 0.f;
#pragma unroll
        for (int i = 0; i < 8; ++i) {
            float e0 = __expf(ev[i].x - mx);
            float e1 = __expf(ev[i].y - mx);
            float e2 = __expf(ev[i].z - mx);
            float e3 = __expf(ev[i].w - mx);
            ev[i] = (f32x4){e0, e1, e2, e3};
            sum += (e0 + e1) + (e2 + e3);
        }
#pragma unroll
        for (int mk = 1; mk < 16; mk <<= 1) sum += __shfl_xor(sum, mk);
        const float inv = 1.0f / sum;

        // scale + store att (NT) + pack P (no exp, no recompute)
        f32x4* attrow = (f32x4*)(att + rowg * N);
        unsigned short* Prow = P + r * 512;
        const int r7 = r & 7, chalf = (c & 1) * 4;
#pragma unroll
        for (int i = 0; i < 8; ++i) {
            float e0 = ev[i].x * inv;
            float e1 = ev[i].y * inv;
            float e2 = ev[i].z * inv;
            float e3 = ev[i].w * inv;
            __builtin_nontemporal_store((f32x4){e0, e1, e2, e3},
                                        attrow + i * 16 + c);
            int slot = i * 8 + (c >> 1);
            int S = slot ^ r7 ^ (slot >> 3);
            ushort4 pk = { f2b(e0), f2b(e1), f2b(e2), f2b(e3) };
            *(ushort4*)&Prow[S * 8 + chalf] = pk;
        }
    }
    __syncthreads();

    // ---- phase 2: hp[m0..m0+64][0..256] = P @ WhT^T, K = 512 ----
    // 16 waves; wave w computes the 64x16 strip at n = w*16.
    const int wn  = w * 16;
    const int l15 = lane & 15, q = lane >> 4;
    const unsigned short* bRow = WhT + ((size_t)bb * DOUT + wn + l15) * N + q * 8;
    int rm7[4], rmBase[4];
#pragma unroll
    for (int mi = 0; mi < 4; ++mi) {
        int rm = mi * 16 + l15;
        rm7[mi] = rm & 7;
        rmBase[mi] = rm * 512;
    }

    f32x4 acc[4];
#pragma unroll
    for (int i = 0; i < 4; ++i) acc[i] = (f32x4){0.f, 0.f, 0.f, 0.f};

#pragma unroll 4
    for (int k0 = 0; k0 < N; k0 += 32) {
        const int slot = (k0 >> 3) + q;          // 0..63
        const int hi = slot >> 3;
        bf16x8 af[4];
        bf16x8 bfr = *(const bf16x8*)(bRow + k0);
#pragma unroll
        for (int mi = 0; mi < 4; ++mi) {
            int S = slot ^ rm7[mi] ^ hi;
            af[mi] = *(const bf16x8*)&P[rmBase[mi] + S * 8];
        }
#pragma unroll
        for (int mi = 0; mi < 4; ++mi)
            acc[mi] = __builtin_amdgcn_mfma_f32_16x16x32_bf16(
                af[mi], bfr, acc[mi], 0, 0, 0);
    }

#pragma unroll
    for (int mi = 0; mi < 4; ++mi) {
#pragma unroll
        for (int rr = 0; rr < 4; ++rr) {
            int m = m0 + mi * 16 + q * 4 + rr;
            int n = wn + l15;
            hp[((size_t)bb * N + m) * DOUT + n] = acc[mi][rr];
        }
    }
}

// ---------------------------------------------------------------------------
extern "C" void kernel_launch(void* const* d_in, const int* in_sizes, int n_in,
                              void* d_out, int out_size, void* d_ws, size_t ws_size,
                              hipStream_t stream) {
    const float* h         = (const float*)d_in[0];
    const int*   adj       = (const int*)  d_in[1];
    const int*   positions = (const int*)  d_in[2];
    const float* W         = (const float*)d_in[3];
    const float* a1        = (const float*)d_in[4];
    const float* a2        = (const float*)d_in[5];
    const float* pos_table = (const float*)d_in[6];

    float* out     = (float*)d_out;
    float* h_prime = out;                           // [B,N,DOUT]
    float* att     = out + (size_t)B * N * DOUT;    // [B,N,N]

    char* ws = (char*)d_ws;
    unsigned short* WT  = (unsigned short*)ws;                  // 0.39 MB
    unsigned short* WhT = (unsigned short*)(ws + 393216);       // 8.39 MB
    float*          s1  = (float*)(ws + 8781824);               // 64 KB
    float*          s2  = s1 + (size_t)B * N;

    // 0) zero s1/s2 for the fused atomics
    (void)hipMemsetAsync(s1, 0, (size_t)2 * B * N * sizeof(float), stream);
    // 1) W -> WT bf16
    wt_kernel<<<48, 256, 0, stream>>>(W, WT);
    // 2) Wh GEMM (round-5 form) + pos_emb -> WhT bf16, fused s1/s2
    wh_mfma<<<512, 256, 0, stream>>>(h, WT, positions, pos_table, a1, a2, WhT, s1, s2);
    // 3) fused softmax + h_prime GEMM (1-pass softmax, NT streams, XCD-colocated)
    attn_hp<<<256, 1024, 0, stream>>>(s1, s2, adj, WhT, att, h_prime);
}